// Round 1
// baseline (1205.600 us; speedup 1.0000x reference)
//
#include <hip/hip_runtime.h>
#include <cstdint>

#define NP 200000
#define NA 100000
#define EW 300000
#define EC 300000
#define HID 128
#define FIN_P 256
#define FIN_A 128
#define NOUT 16
#define ATT_SCALE 0.17677669529663687f  // 1/sqrt(32)

// ---------- helpers ----------
__device__ __forceinline__ unsigned enc_f(float f) {
  unsigned b = __float_as_uint(f);
  return (b & 0x80000000u) ? ~b : (b | 0x80000000u);
}
__device__ __forceinline__ float dec_f(unsigned u) {
  return __uint_as_float((u & 0x80000000u) ? (u ^ 0x80000000u) : ~u);
}
__device__ __forceinline__ float gelu_f(float x) {
  return 0.5f * x * (1.0f + erff(x * 0.70710678118654752f));
}

// ---------- tiny: combined per-relation K/V weights ----------
// Wc[:, h*32+e] = sum_d W[:, h*32+d] * rel[h,d,e];  bc likewise from bias.
__global__ void combine_w(
    const float* __restrict__ kwa, const float* __restrict__ kba, const float* __restrict__ arw,
    const float* __restrict__ vwa, const float* __restrict__ vba, const float* __restrict__ mrw,
    const float* __restrict__ kwp, const float* __restrict__ kbp, const float* __restrict__ arc,
    const float* __restrict__ vwp, const float* __restrict__ vbp, const float* __restrict__ mrc,
    float* __restrict__ wc, float* __restrict__ bc)
{
  const float *W, *b, *rel;
  switch (blockIdx.x) {
    case 0:  W = kwa; b = kba; rel = arw; break;  // kr_writes (author)
    case 1:  W = vwa; b = vba; rel = mrw; break;  // vr_writes (author)
    case 2:  W = kwp; b = kbp; rel = arc; break;  // kr_cites (paper)
    default: W = vwp; b = vbp; rel = mrc; break;  // vr_cites (paper)
  }
  float* Wo = wc + (size_t)blockIdx.x * (HID * HID);
  float* bo = bc + (size_t)blockIdx.x * HID;
  for (int idx = threadIdx.x; idx < HID * HID; idx += blockDim.x) {
    int r = idx >> 7, c = idx & 127, h = c >> 5, e = c & 31;
    float s = 0.f;
    #pragma unroll
    for (int d = 0; d < 32; ++d) s += W[r * HID + h * 32 + d] * rel[h * 1024 + d * 32 + e];
    Wo[idx] = s;
  }
  for (int c = threadIdx.x; c < HID; c += blockDim.x) {
    int h = c >> 5, e = c & 31;
    float s = 0.f;
    #pragma unroll
    for (int d = 0; d < 32; ++d) s += b[h * 32 + d] * rel[h * 1024 + d * 32 + e];
    bo[c] = s;
  }
}

// ---------- epilogue weight prep ----------
// Wg = beta*(a_w @ W2) [128,16]; Wh = (1-beta)*W2; bo = beta*(a_b @ W2) + b2
__global__ void epi_prep(const float* __restrict__ aw, const float* __restrict__ ab,
                         const float* __restrict__ skip, const float* __restrict__ W2,
                         const float* __restrict__ b2,
                         float* __restrict__ Wg, float* __restrict__ Wh, float* __restrict__ bo)
{
  float beta = 1.0f / (1.0f + expf(-skip[0]));
  int tid = threadIdx.x;
  for (int idx = tid; idx < 128 * 16; idx += 256) {
    int r = idx >> 4, c = idx & 15;
    float s = 0.f;
    for (int k = 0; k < 128; ++k) s += aw[r * 128 + k] * W2[k * 16 + c];
    Wg[idx] = beta * s;
    Wh[idx] = (1.0f - beta) * W2[idx];
  }
  if (tid < 16) {
    float s = 0.f;
    for (int k = 0; k < 128; ++k) s += ab[k] * W2[k * 16 + tid];
    bo[tid] = beta * s + b2[tid];
  }
}

// ---------- generic f32 GEMM, N=128 fixed: C[M,128] = act(A[M,K] @ W[K,128] + bias) ----------
// 64-row tile, 256 threads, 4x8 register tile per thread.
__global__ __launch_bounds__(256) void gemm128_f32(
    const float* __restrict__ A, const float* __restrict__ W,
    const float* __restrict__ bias, float* __restrict__ C,
    int M, int K, int relu)
{
  __shared__ float As[32][68];   // [k][row], stride 68 to dodge store-phase conflicts
  __shared__ float Ws[32][128];  // [k][col]
  const int tid = threadIdx.x;
  const int tr = tid & 15;   // row group: rows tr*4..tr*4+3
  const int tc = tid >> 4;   // col group: cols tc*8..tc*8+7
  const int row0 = blockIdx.x * 64;

  float acc[4][8];
  #pragma unroll
  for (int i = 0; i < 4; ++i)
    #pragma unroll
    for (int j = 0; j < 8; ++j) acc[i][j] = 0.f;

  for (int kt = 0; kt < K; kt += 32) {
    // A tile: 64 rows x 32 k  (512 float4, 2 per thread, coalesced)
    #pragma unroll
    for (int i = 0; i < 2; ++i) {
      int idx = tid + i * 256;
      int r = idx >> 3;
      int kq = (idx & 7) << 2;
      float4 a = make_float4(0.f, 0.f, 0.f, 0.f);
      if (row0 + r < M) a = *(const float4*)(A + (size_t)(row0 + r) * K + kt + kq);
      As[kq + 0][r] = a.x; As[kq + 1][r] = a.y; As[kq + 2][r] = a.z; As[kq + 3][r] = a.w;
    }
    // W tile: 32 x 128 (1024 float4, 4 per thread, coalesced)
    #pragma unroll
    for (int i = 0; i < 4; ++i) {
      int idx = tid + i * 256;
      int kk = idx >> 5;
      int c4 = (idx & 31) << 2;
      *(float4*)&Ws[kk][c4] = *(const float4*)(W + (size_t)(kt + kk) * HID + c4);
    }
    __syncthreads();
    #pragma unroll
    for (int kk = 0; kk < 32; ++kk) {
      float4 a  = *(const float4*)&As[kk][tr << 2];
      float4 b0 = *(const float4*)&Ws[kk][tc << 3];
      float4 b1 = *(const float4*)&Ws[kk][(tc << 3) + 4];
      float av[4] = {a.x, a.y, a.z, a.w};
      float bv[8] = {b0.x, b0.y, b0.z, b0.w, b1.x, b1.y, b1.z, b1.w};
      #pragma unroll
      for (int i = 0; i < 4; ++i)
        #pragma unroll
        for (int j = 0; j < 8; ++j)
          acc[i][j] = fmaf(av[i], bv[j], acc[i][j]);
    }
    __syncthreads();
  }

  float4 bb0 = *(const float4*)(bias + (tc << 3));
  float4 bb1 = *(const float4*)(bias + (tc << 3) + 4);
  float bv[8] = {bb0.x, bb0.y, bb0.z, bb0.w, bb1.x, bb1.y, bb1.z, bb1.w};
  #pragma unroll
  for (int i = 0; i < 4; ++i) {
    int r = row0 + (tr << 2) + i;
    if (r < M) {
      float o[8];
      #pragma unroll
      for (int j = 0; j < 8; ++j) {
        o[j] = acc[i][j] + bv[j];
        if (relu) o[j] = fmaxf(o[j], 0.f);
      }
      *(float4*)(C + (size_t)r * HID + (tc << 3))     = make_float4(o[0], o[1], o[2], o[3]);
      *(float4*)(C + (size_t)r * HID + (tc << 3) + 4) = make_float4(o[4], o[5], o[6], o[7]);
    }
  }
}

// ---------- edge pass A: alpha + segment max ----------
__global__ void edge_alpha(int E, const int* __restrict__ src, const int* __restrict__ dst,
                           const float* __restrict__ kr, const float* __restrict__ q,
                           const float* __restrict__ p_rel,
                           float* __restrict__ alpha, unsigned* __restrict__ mbuf)
{
  int items = E * 4;
  for (int it = blockIdx.x * blockDim.x + threadIdx.x; it < items; it += gridDim.x * blockDim.x) {
    int e = it >> 2, h = it & 3;
    int si = src[e], di = dst[e];
    const float4* qp = (const float4*)(q + (size_t)di * HID + h * 32);
    const float4* kp = (const float4*)(kr + (size_t)si * HID + h * 32);
    float dot = 0.f;
    #pragma unroll
    for (int j = 0; j < 8; ++j) {
      float4 a = qp[j], b = kp[j];
      dot += a.x * b.x + a.y * b.y + a.z * b.z + a.w * b.w;
    }
    float al = dot * p_rel[h] * ATT_SCALE;
    alpha[it] = al;
    atomicMax(mbuf + (size_t)di * 4 + h, enc_f(al));
  }
}

// ---------- edge pass B: e = exp(a - m), segment sum ----------
__global__ void edge_expsum(int E, const int* __restrict__ dst,
                            float* __restrict__ alpha, const unsigned* __restrict__ mbuf,
                            float* __restrict__ sbuf)
{
  int items = E * 4;
  for (int it = blockIdx.x * blockDim.x + threadIdx.x; it < items; it += gridDim.x * blockDim.x) {
    int e = it >> 2, h = it & 3;
    int di = dst[e];
    float m = dec_f(mbuf[(size_t)di * 4 + h]);
    float ev = expf(alpha[it] - m);
    alpha[it] = ev;
    atomicAdd(sbuf + (size_t)di * 4 + h, ev);
  }
}

// ---------- edge pass C: out_p[dst] += vr[src] * (e / (s+eps)) ----------
__global__ void edge_scatter(int E, const int* __restrict__ src, const int* __restrict__ dst,
                             const float* __restrict__ vr, const float* __restrict__ alpha,
                             const float* __restrict__ sbuf, float* __restrict__ out_p)
{
  int gtid = blockIdx.x * blockDim.x + threadIdx.x;
  int wave = gtid >> 6;
  int lane = threadIdx.x & 63;
  int nwaves = (gridDim.x * blockDim.x) >> 6;
  for (int e = wave; e < E; e += nwaves) {
    int si = src[e], di = dst[e];
    int h0 = lane >> 5, h1 = 2 + (lane >> 5);
    float w0 = alpha[(size_t)e * 4 + h0] / (sbuf[(size_t)di * 4 + h0] + 1e-16f);
    float w1 = alpha[(size_t)e * 4 + h1] / (sbuf[(size_t)di * 4 + h1] + 1e-16f);
    float v0 = vr[(size_t)si * HID + lane];
    float v1 = vr[(size_t)si * HID + 64 + lane];
    atomicAdd(out_p + (size_t)di * HID + lane, v0 * w0);
    atomicAdd(out_p + (size_t)di * HID + 64 + lane, v1 * w1);
  }
}

// ---------- fused epilogue: out = gelu(out_p)@Wg + hp@Wh + bo ----------
__global__ __launch_bounds__(256) void epilogue_k(
    const float* __restrict__ out_p, const float* __restrict__ hp,
    const float* __restrict__ Wg, const float* __restrict__ Wh,
    const float* __restrict__ bo, float* __restrict__ out)
{
  __shared__ float Ts[64][129];
  __shared__ float Wgs[128][16];
  __shared__ float Whs[128][16];
  __shared__ float bs[16];
  int tid = threadIdx.x;
  int row0 = blockIdx.x * 64;

  #pragma unroll
  for (int i = 0; i < 2; ++i) {
    int idx = tid + i * 256;  // 512 float4 = 2048 floats
    *(float4*)&Wgs[idx >> 2][(idx & 3) << 2] = *(const float4*)(Wg + (size_t)idx * 4);
    *(float4*)&Whs[idx >> 2][(idx & 3) << 2] = *(const float4*)(Wh + (size_t)idx * 4);
  }
  if (tid < 16) bs[tid] = bo[tid];

  // pass 1: gelu(out_p) tile
  #pragma unroll
  for (int i = 0; i < 8; ++i) {
    int idx = tid + i * 256;
    int r = idx >> 5, c4 = (idx & 31) << 2;
    float4 g = *(const float4*)(out_p + (size_t)(row0 + r) * HID + c4);
    Ts[r][c4 + 0] = gelu_f(g.x); Ts[r][c4 + 1] = gelu_f(g.y);
    Ts[r][c4 + 2] = gelu_f(g.z); Ts[r][c4 + 3] = gelu_f(g.w);
  }
  __syncthreads();

  int row = tid & 63, cg = tid >> 6;
  float acc[4];
  #pragma unroll
  for (int j = 0; j < 4; ++j) acc[j] = bs[cg * 4 + j];
  for (int k = 0; k < 128; ++k) {
    float g = Ts[row][k];
    float4 w = *(const float4*)&Wgs[k][cg << 2];
    acc[0] = fmaf(g, w.x, acc[0]); acc[1] = fmaf(g, w.y, acc[1]);
    acc[2] = fmaf(g, w.z, acc[2]); acc[3] = fmaf(g, w.w, acc[3]);
  }
  __syncthreads();

  // pass 2: hp tile (reuse Ts)
  #pragma unroll
  for (int i = 0; i < 8; ++i) {
    int idx = tid + i * 256;
    int r = idx >> 5, c4 = (idx & 31) << 2;
    float4 h = *(const float4*)(hp + (size_t)(row0 + r) * HID + c4);
    Ts[r][c4 + 0] = h.x; Ts[r][c4 + 1] = h.y; Ts[r][c4 + 2] = h.z; Ts[r][c4 + 3] = h.w;
  }
  __syncthreads();
  for (int k = 0; k < 128; ++k) {
    float h = Ts[row][k];
    float4 w = *(const float4*)&Whs[k][cg << 2];
    acc[0] = fmaf(h, w.x, acc[0]); acc[1] = fmaf(h, w.y, acc[1]);
    acc[2] = fmaf(h, w.z, acc[2]); acc[3] = fmaf(h, w.w, acc[3]);
  }
  *(float4*)(out + (size_t)(row0 + row) * NOUT + (cg << 2)) =
      make_float4(acc[0], acc[1], acc[2], acc[3]);
}

// ---------- launch ----------
extern "C" void kernel_launch(void* const* d_in, const int* in_sizes, int n_in,
                              void* d_out, int out_size, void* d_ws, size_t ws_size,
                              hipStream_t stream)
{
  (void)in_sizes; (void)n_in; (void)out_size; (void)ws_size;
  const float* x_paper      = (const float*)d_in[0];
  const float* x_author     = (const float*)d_in[1];
  const int*   writes_src   = (const int*)d_in[2];
  const int*   writes_dst   = (const int*)d_in[3];
  const int*   cites_src    = (const int*)d_in[4];
  const int*   cites_dst    = (const int*)d_in[5];
  const float* lin_paper_w  = (const float*)d_in[6];
  const float* lin_paper_b  = (const float*)d_in[7];
  const float* lin_author_w = (const float*)d_in[8];
  const float* lin_author_b = (const float*)d_in[9];
  const float* lin_out_w    = (const float*)d_in[10];
  const float* lin_out_b    = (const float*)d_in[11];
  const float* k_w_paper    = (const float*)d_in[12];
  const float* k_b_paper    = (const float*)d_in[13];
  const float* q_w_paper    = (const float*)d_in[14];
  const float* q_b_paper    = (const float*)d_in[15];
  const float* v_w_paper    = (const float*)d_in[16];
  const float* v_b_paper    = (const float*)d_in[17];
  const float* a_w_paper    = (const float*)d_in[18];
  const float* a_b_paper    = (const float*)d_in[19];
  const float* skip_paper   = (const float*)d_in[20];
  const float* k_w_author   = (const float*)d_in[21];
  const float* k_b_author   = (const float*)d_in[22];
  const float* v_w_author   = (const float*)d_in[25];
  const float* v_b_author   = (const float*)d_in[26];
  const float* a_rel_writes = (const float*)d_in[30];
  const float* m_rel_writes = (const float*)d_in[31];
  const float* p_rel_writes = (const float*)d_in[32];
  const float* a_rel_cites  = (const float*)d_in[33];
  const float* m_rel_cites  = (const float*)d_in[34];
  const float* p_rel_cites  = (const float*)d_in[35];

  float* ws = (float*)d_ws;
  size_t off = 0;
  auto nxt = [&](size_t n) { float* p = ws + off; off += n; return p; };
  float*    hp    = nxt((size_t)NP * HID);
  float*    ha    = nxt((size_t)NA * HID);
  float*    q_p   = nxt((size_t)NP * HID);
  float*    kr_c  = nxt((size_t)NP * HID);
  float*    vr_c  = nxt((size_t)NP * HID);
  float*    kr_w  = nxt((size_t)NA * HID);
  float*    vr_w  = nxt((size_t)NA * HID);
  float*    outp  = nxt((size_t)NP * HID);
  unsigned* mbuf  = (unsigned*)nxt((size_t)NP * 4);
  float*    sbuf  = nxt((size_t)NP * 4);
  float*    alpha = nxt((size_t)EW * 4);
  float*    wc    = nxt(4 * 16384);
  float*    bc    = nxt(4 * 128);
  float*    Wg    = nxt(2048);
  float*    Wh    = nxt(2048);
  float*    bo    = nxt(16);

  combine_w<<<4, 256, 0, stream>>>(k_w_author, k_b_author, a_rel_writes,
                                   v_w_author, v_b_author, m_rel_writes,
                                   k_w_paper, k_b_paper, a_rel_cites,
                                   v_w_paper, v_b_paper, m_rel_cites, wc, bc);
  epi_prep<<<1, 256, 0, stream>>>(a_w_paper, a_b_paper, skip_paper, lin_out_w, lin_out_b,
                                  Wg, Wh, bo);

  gemm128_f32<<<(NP + 63) / 64, 256, 0, stream>>>(x_paper, lin_paper_w, lin_paper_b, hp, NP, FIN_P, 1);
  gemm128_f32<<<(NA + 63) / 64, 256, 0, stream>>>(x_author, lin_author_w, lin_author_b, ha, NA, FIN_A, 1);
  gemm128_f32<<<(NP + 63) / 64, 256, 0, stream>>>(hp, q_w_paper, q_b_paper, q_p, NP, HID, 0);
  gemm128_f32<<<(NP + 63) / 64, 256, 0, stream>>>(hp, wc + 2 * 16384, bc + 2 * 128, kr_c, NP, HID, 0);
  gemm128_f32<<<(NP + 63) / 64, 256, 0, stream>>>(hp, wc + 3 * 16384, bc + 3 * 128, vr_c, NP, HID, 0);
  gemm128_f32<<<(NA + 63) / 64, 256, 0, stream>>>(ha, wc + 0 * 16384, bc + 0 * 128, kr_w, NA, HID, 0);
  gemm128_f32<<<(NA + 63) / 64, 256, 0, stream>>>(ha, wc + 1 * 16384, bc + 1 * 128, vr_w, NA, HID, 0);

  hipMemsetAsync(outp, 0, (size_t)NP * HID * sizeof(float), stream);

  // relation: writes (author -> paper)
  hipMemsetAsync(mbuf, 0, (size_t)NP * 4 * sizeof(unsigned), stream);
  hipMemsetAsync(sbuf, 0, (size_t)NP * 4 * sizeof(float), stream);
  edge_alpha<<<(EW * 4 + 255) / 256, 256, 0, stream>>>(EW, writes_src, writes_dst, kr_w, q_p,
                                                       p_rel_writes, alpha, mbuf);
  edge_expsum<<<(EW * 4 + 255) / 256, 256, 0, stream>>>(EW, writes_dst, alpha, mbuf, sbuf);
  edge_scatter<<<1024, 256, 0, stream>>>(EW, writes_src, writes_dst, vr_w, alpha, sbuf, outp);

  // relation: cites (paper -> paper)
  hipMemsetAsync(mbuf, 0, (size_t)NP * 4 * sizeof(unsigned), stream);
  hipMemsetAsync(sbuf, 0, (size_t)NP * 4 * sizeof(float), stream);
  edge_alpha<<<(EC * 4 + 255) / 256, 256, 0, stream>>>(EC, cites_src, cites_dst, kr_c, q_p,
                                                       p_rel_cites, alpha, mbuf);
  edge_expsum<<<(EC * 4 + 255) / 256, 256, 0, stream>>>(EC, cites_dst, alpha, mbuf, sbuf);
  edge_scatter<<<1024, 256, 0, stream>>>(EC, cites_src, cites_dst, vr_c, alpha, sbuf, outp);

  epilogue_k<<<(NP + 63) / 64, 256, 0, stream>>>(outp, hp, Wg, Wh, bo, (float*)d_out);
}

// Round 2
// 778.365 us; speedup vs baseline: 1.5489x; 1.5489x over previous
//
#include <hip/hip_runtime.h>
#include <cstdint>

#define NP 200000
#define NA 100000
#define EW 300000
#define EC 300000
#define HID 128
#define FIN_P 256
#define FIN_A 128
#define NOUT 16
#define ATT_SCALE 0.17677669529663687f  // 1/sqrt(32)

typedef short s8v __attribute__((ext_vector_type(8)));
typedef float f32x4 __attribute__((ext_vector_type(4)));
typedef unsigned short ushort_t;

// ---------- helpers ----------
__device__ __forceinline__ unsigned enc_f(float f) {
  unsigned b = __float_as_uint(f);
  return (b & 0x80000000u) ? ~b : (b | 0x80000000u);
}
__device__ __forceinline__ float dec_f(unsigned u) {
  return __uint_as_float((u & 0x80000000u) ? (u ^ 0x80000000u) : ~u);
}
__device__ __forceinline__ float gelu_f(float x) {
  return 0.5f * x * (1.0f + erff(x * 0.70710678118654752f));
}
__device__ __forceinline__ ushort_t f2bf(float f) {  // RNE, no NaN handling (no NaNs here)
  unsigned u = __float_as_uint(f);
  return (ushort_t)((u + 0x7FFFu + ((u >> 16) & 1u)) >> 16);
}
__device__ __forceinline__ unsigned pack2bf(float a, float b) {
  return (unsigned)f2bf(a) | ((unsigned)f2bf(b) << 16);
}
__device__ __forceinline__ float bflo(unsigned u) { return __uint_as_float(u << 16); }
__device__ __forceinline__ float bfhi(unsigned u) { return __uint_as_float(u & 0xFFFF0000u); }

__device__ __forceinline__ float dot8bf(uint4 a, uint4 b) {
  const unsigned* pa = (const unsigned*)&a;
  const unsigned* pb = (const unsigned*)&b;
  float s = 0.f;
  #pragma unroll
  for (int w = 0; w < 4; ++w)
    s += bflo(pa[w]) * bflo(pb[w]) + bfhi(pa[w]) * bfhi(pb[w]);
  return s;
}

// ---------- weight prep: all GEMM B-matrices -> bf16, TRANSPOSED [n][k] ----------
// Wall layout (ushort): set0 Wq[128][128], set1 Wkc, set2 Wvc, set3 Wkw, set4 Wvw,
//                       set5 Wa[128][128], then Wp[128][256] at +6*16384.
// Ball (float): [5][128] biases for sets 0..4 (q, kr_c, vr_c, kr_w, vr_w).
__global__ void prep_weights(
    const float* __restrict__ qw,  const float* __restrict__ qb,
    const float* __restrict__ kwp, const float* __restrict__ kbp, const float* __restrict__ arc,
    const float* __restrict__ vwp, const float* __restrict__ vbp, const float* __restrict__ mrc,
    const float* __restrict__ kwa, const float* __restrict__ kba, const float* __restrict__ arw,
    const float* __restrict__ vwa, const float* __restrict__ vba, const float* __restrict__ mrw,
    const float* __restrict__ lpw, const float* __restrict__ law,
    ushort_t* __restrict__ Wall, float* __restrict__ Ball)
{
  const int b = blockIdx.x, tid = threadIdx.x;
  if (b == 0) {                    // plain transpose: q weights
    for (int idx = tid; idx < 16384; idx += 256) {
      int c = idx >> 7, r = idx & 127;
      Wall[idx] = f2bf(qw[r * 128 + c]);
    }
    for (int c = tid; c < 128; c += 256) Ball[c] = qb[c];
  } else if (b <= 4) {             // combined per-relation weights
    const float *W, *bias, *rel;
    switch (b) {
      case 1:  W = kwp; bias = kbp; rel = arc; break;
      case 2:  W = vwp; bias = vbp; rel = mrc; break;
      case 3:  W = kwa; bias = kba; rel = arw; break;
      default: W = vwa; bias = vba; rel = mrw; break;
    }
    for (int idx = tid; idx < 16384; idx += 256) {
      int c = idx >> 7, r = idx & 127, h = c >> 5, e = c & 31;
      float s = 0.f;
      #pragma unroll
      for (int d = 0; d < 32; ++d) s += W[r * 128 + h * 32 + d] * rel[h * 1024 + d * 32 + e];
      Wall[b * 16384 + idx] = f2bf(s);
    }
    for (int c = tid; c < 128; c += 256) {
      int h = c >> 5, e = c & 31;
      float s = 0.f;
      #pragma unroll
      for (int d = 0; d < 32; ++d) s += bias[h * 32 + d] * rel[h * 1024 + d * 32 + e];
      Ball[b * 128 + c] = s;
    }
  } else if (b == 5) {             // author input-proj weights
    for (int idx = tid; idx < 16384; idx += 256) {
      int c = idx >> 7, r = idx & 127;
      Wall[5 * 16384 + idx] = f2bf(law[r * 128 + c]);
    }
  } else {                         // paper input-proj weights [128 n][256 k]
    for (int idx = tid; idx < 32768; idx += 256) {
      int c = idx >> 8, r = idx & 255;
      Wall[6 * 16384 + idx] = f2bf(lpw[r * 128 + c]);
    }
  }
}

// ---------- epilogue weight prep ----------
__global__ void epi_prep(const float* __restrict__ aw, const float* __restrict__ ab,
                         const float* __restrict__ skip, const float* __restrict__ W2,
                         const float* __restrict__ b2,
                         float* __restrict__ Wg, float* __restrict__ Wh, float* __restrict__ bo)
{
  float beta = 1.0f / (1.0f + expf(-skip[0]));
  int tid = threadIdx.x;
  for (int idx = tid; idx < 128 * 16; idx += 256) {
    int r = idx >> 4, c = idx & 15;
    float s = 0.f;
    for (int k = 0; k < 128; ++k) s += aw[r * 128 + k] * W2[k * 16 + c];
    Wg[idx] = beta * s;
    Wh[idx] = (1.0f - beta) * W2[idx];
  }
  if (tid < 16) {
    float s = 0.f;
    for (int k = 0; k < 128; ++k) s += ab[k] * W2[k * 16 + tid];
    bo[tid] = beta * s + b2[tid];
  }
}

// ---------- bf16 MFMA GEMM: C[M,128](bf16) = act(A[M,KT] @ W^T + bias) ----------
// 128x128 block tile, 4 waves (2x2), 4x4 16x16x32 frags per wave, BK=32.
// LDS layout [kgroup][idx][8 bf16] -> conflict-floor ds_read_b128.
// blockIdx.y selects weight set / bias / output buffer (stride cstride).
template <int KT, bool AF32, bool RELU>
__global__ __launch_bounds__(256) void gemm_mfma(
    const void* __restrict__ Ap, const ushort_t* __restrict__ Wbase,
    const float* __restrict__ bbase, ushort_t* __restrict__ Cbase,
    int M, long long cstride)
{
  __shared__ ushort_t As[4][128][8];   // 8 KB
  __shared__ ushort_t Bs[4][128][8];   // 8 KB
  const int tid  = threadIdx.x;
  const int lane = tid & 63;
  const int wv   = tid >> 6;
  const int wr   = wv >> 1, wc = wv & 1;
  const int l15  = lane & 15, kgl = lane >> 4;
  const int row0 = blockIdx.x * 128;
  const ushort_t* W   = Wbase + (size_t)blockIdx.y * 128 * KT;
  const float* bias   = bbase + (size_t)blockIdx.y * 128;
  ushort_t* C         = Cbase + (size_t)blockIdx.y * cstride;

  f32x4 acc[4][4];
  #pragma unroll
  for (int i = 0; i < 4; ++i)
    #pragma unroll
    for (int j = 0; j < 4; ++j) acc[i][j] = (f32x4){0.f, 0.f, 0.f, 0.f};

  for (int kt = 0; kt < KT; kt += 32) {
    // ---- stage A tile: 128 rows x 32 k (bf16) ----
    #pragma unroll
    for (int half = 0; half < 2; ++half) {
      int slot = half * 256 + tid;           // 0..511 = (kg, r)
      int kg = slot >> 7, r = slot & 127;
      int grow = row0 + r; if (grow > M - 1) grow = M - 1;   // clamp tail
      if (AF32) {
        const float* ga = (const float*)Ap + (size_t)grow * KT + kt + kg * 8;
        float4 a0 = *(const float4*)ga;
        float4 a1 = *(const float4*)(ga + 4);
        uint4 v;
        v.x = pack2bf(a0.x, a0.y); v.y = pack2bf(a0.z, a0.w);
        v.z = pack2bf(a1.x, a1.y); v.w = pack2bf(a1.z, a1.w);
        *(uint4*)&As[kg][r][0] = v;
      } else {
        *(uint4*)&As[kg][r][0] =
            *(const uint4*)((const ushort_t*)Ap + (size_t)grow * KT + kt + kg * 8);
      }
    }
    // ---- stage B tile: 128 cols x 32 k (bf16, W is [n][k]) ----
    #pragma unroll
    for (int half = 0; half < 2; ++half) {
      int slot = half * 256 + tid;
      int kg = slot >> 7, c = slot & 127;
      *(uint4*)&Bs[kg][c][0] = *(const uint4*)(W + (size_t)c * KT + kt + kg * 8);
    }
    __syncthreads();

    const s8v* As8 = (const s8v*)&As[0][0][0];
    const s8v* Bs8 = (const s8v*)&Bs[0][0][0];
    s8v af[4], bfv[4];
    #pragma unroll
    for (int i = 0; i < 4; ++i) af[i]  = As8[kgl * 128 + wr * 64 + i * 16 + l15];
    #pragma unroll
    for (int j = 0; j < 4; ++j) bfv[j] = Bs8[kgl * 128 + wc * 64 + j * 16 + l15];
    #pragma unroll
    for (int i = 0; i < 4; ++i)
      #pragma unroll
      for (int j = 0; j < 4; ++j)
        acc[i][j] = __builtin_amdgcn_mfma_f32_16x16x32_bf16(af[i], bfv[j], acc[i][j], 0, 0, 0);
    __syncthreads();
  }

  // ---- epilogue: bias (+relu), bf16 store. D: col=lane&15, row=(lane>>4)*4+reg ----
  float bv[4];
  #pragma unroll
  for (int j = 0; j < 4; ++j) bv[j] = bias[wc * 64 + j * 16 + l15];
  #pragma unroll
  for (int i = 0; i < 4; ++i) {
    #pragma unroll
    for (int r = 0; r < 4; ++r) {
      int row = row0 + wr * 64 + i * 16 + kgl * 4 + r;
      if (row < M) {
        #pragma unroll
        for (int j = 0; j < 4; ++j) {
          float v = acc[i][j][r] + bv[j];
          if (RELU) v = fmaxf(v, 0.f);
          C[(size_t)row * 128 + wc * 64 + j * 16 + l15] = f2bf(v);
        }
      }
    }
  }
}

// ---------- edge pass A: alpha + segment max (bf16 q/kr) ----------
__global__ void edge_alpha(int E, const int* __restrict__ src, const int* __restrict__ dst,
                           const ushort_t* __restrict__ kr, const ushort_t* __restrict__ q,
                           const float* __restrict__ p_rel,
                           float* __restrict__ alpha, unsigned* __restrict__ mbuf)
{
  int items = E * 4;
  for (int it = blockIdx.x * blockDim.x + threadIdx.x; it < items; it += gridDim.x * blockDim.x) {
    int e = it >> 2, h = it & 3;
    int si = src[e], di = dst[e];
    const uint4* qp = (const uint4*)(q + (size_t)di * HID + h * 32);
    const uint4* kp = (const uint4*)(kr + (size_t)si * HID + h * 32);
    float dot = 0.f;
    #pragma unroll
    for (int c = 0; c < 4; ++c) dot += dot8bf(qp[c], kp[c]);
    float al = dot * p_rel[h] * ATT_SCALE;
    alpha[it] = al;
    atomicMax(mbuf + (size_t)di * 4 + h, enc_f(al));
  }
}

// ---------- edge pass B: e = exp(a - m), segment sum ----------
__global__ void edge_expsum(int E, const int* __restrict__ dst,
                            float* __restrict__ alpha, const unsigned* __restrict__ mbuf,
                            float* __restrict__ sbuf)
{
  int items = E * 4;
  for (int it = blockIdx.x * blockDim.x + threadIdx.x; it < items; it += gridDim.x * blockDim.x) {
    int e = it >> 2, h = it & 3;
    int di = dst[e];
    float m = dec_f(mbuf[(size_t)di * 4 + h]);
    float ev = expf(alpha[it] - m);
    alpha[it] = ev;
    atomicAdd(sbuf + (size_t)di * 4 + h, ev);
  }
}

// ---------- edge pass C: out_p[dst] += vr[src] * (e / (s+eps))  (bf16 vr) ----------
__global__ void edge_scatter(int E, const int* __restrict__ src, const int* __restrict__ dst,
                             const ushort_t* __restrict__ vr, const float* __restrict__ alpha,
                             const float* __restrict__ sbuf, float* __restrict__ out_p)
{
  int gtid = blockIdx.x * blockDim.x + threadIdx.x;
  int wave = gtid >> 6;
  int lane = threadIdx.x & 63;
  int nwaves = (gridDim.x * blockDim.x) >> 6;
  for (int e = wave; e < E; e += nwaves) {
    int si = src[e], di = dst[e];
    int h0 = lane >> 5, h1 = 2 + (lane >> 5);
    float w0 = alpha[(size_t)e * 4 + h0] / (sbuf[(size_t)di * 4 + h0] + 1e-16f);
    float w1 = alpha[(size_t)e * 4 + h1] / (sbuf[(size_t)di * 4 + h1] + 1e-16f);
    float v0 = bflo((unsigned)vr[(size_t)si * HID + lane] << 0) , v1;
    v0 = __uint_as_float(((unsigned)vr[(size_t)si * HID + lane]) << 16);
    v1 = __uint_as_float(((unsigned)vr[(size_t)si * HID + 64 + lane]) << 16);
    atomicAdd(out_p + (size_t)di * HID + lane, v0 * w0);
    atomicAdd(out_p + (size_t)di * HID + 64 + lane, v1 * w1);
  }
}

// ---------- fused epilogue: out = gelu(out_p)@Wg + hp@Wh + bo  (bf16 hp) ----------
__global__ __launch_bounds__(256) void epilogue_k(
    const float* __restrict__ out_p, const ushort_t* __restrict__ hp,
    const float* __restrict__ Wg, const float* __restrict__ Wh,
    const float* __restrict__ bo, float* __restrict__ out)
{
  __shared__ float Ts[64][129];
  __shared__ float Wgs[128][16];
  __shared__ float Whs[128][16];
  __shared__ float bs[16];
  int tid = threadIdx.x;
  int row0 = blockIdx.x * 64;

  #pragma unroll
  for (int i = 0; i < 2; ++i) {
    int idx = tid + i * 256;
    *(float4*)&Wgs[idx >> 2][(idx & 3) << 2] = *(const float4*)(Wg + (size_t)idx * 4);
    *(float4*)&Whs[idx >> 2][(idx & 3) << 2] = *(const float4*)(Wh + (size_t)idx * 4);
  }
  if (tid < 16) bs[tid] = bo[tid];

  // pass 1: gelu(out_p) tile (f32)
  #pragma unroll
  for (int i = 0; i < 8; ++i) {
    int idx = tid + i * 256;
    int r = idx >> 5, c4 = (idx & 31) << 2;
    float4 g = *(const float4*)(out_p + (size_t)(row0 + r) * HID + c4);
    Ts[r][c4 + 0] = gelu_f(g.x); Ts[r][c4 + 1] = gelu_f(g.y);
    Ts[r][c4 + 2] = gelu_f(g.z); Ts[r][c4 + 3] = gelu_f(g.w);
  }
  __syncthreads();

  int row = tid & 63, cg = tid >> 6;
  float acc[4];
  #pragma unroll
  for (int j = 0; j < 4; ++j) acc[j] = bs[cg * 4 + j];
  for (int k = 0; k < 128; ++k) {
    float g = Ts[row][k];
    float4 w = *(const float4*)&Wgs[k][cg << 2];
    acc[0] = fmaf(g, w.x, acc[0]); acc[1] = fmaf(g, w.y, acc[1]);
    acc[2] = fmaf(g, w.z, acc[2]); acc[3] = fmaf(g, w.w, acc[3]);
  }
  __syncthreads();

  // pass 2: hp tile (bf16 -> f32)
  #pragma unroll
  for (int i = 0; i < 4; ++i) {
    int idx = tid + i * 256;           // 1024 uint4 = 64 rows x 128 bf16
    int r = idx >> 4, c8 = (idx & 15) << 3;
    uint4 h = *(const uint4*)(hp + (size_t)(row0 + r) * HID + c8);
    const unsigned* pw = (const unsigned*)&h;
    #pragma unroll
    for (int w = 0; w < 4; ++w) {
      Ts[r][c8 + 2 * w]     = bflo(pw[w]);
      Ts[r][c8 + 2 * w + 1] = bfhi(pw[w]);
    }
  }
  __syncthreads();
  for (int k = 0; k < 128; ++k) {
    float h = Ts[row][k];
    float4 w = *(const float4*)&Whs[k][cg << 2];
    acc[0] = fmaf(h, w.x, acc[0]); acc[1] = fmaf(h, w.y, acc[1]);
    acc[2] = fmaf(h, w.z, acc[2]); acc[3] = fmaf(h, w.w, acc[3]);
  }
  *(float4*)(out + (size_t)(row0 + row) * NOUT + (cg << 2)) =
      make_float4(acc[0], acc[1], acc[2], acc[3]);
}

// ---------- launch ----------
extern "C" void kernel_launch(void* const* d_in, const int* in_sizes, int n_in,
                              void* d_out, int out_size, void* d_ws, size_t ws_size,
                              hipStream_t stream)
{
  (void)in_sizes; (void)n_in; (void)out_size; (void)ws_size;
  const float* x_paper      = (const float*)d_in[0];
  const float* x_author     = (const float*)d_in[1];
  const int*   writes_src   = (const int*)d_in[2];
  const int*   writes_dst   = (const int*)d_in[3];
  const int*   cites_src    = (const int*)d_in[4];
  const int*   cites_dst    = (const int*)d_in[5];
  const float* lin_paper_w  = (const float*)d_in[6];
  const float* lin_paper_b  = (const float*)d_in[7];
  const float* lin_author_w = (const float*)d_in[8];
  const float* lin_author_b = (const float*)d_in[9];
  const float* lin_out_w    = (const float*)d_in[10];
  const float* lin_out_b    = (const float*)d_in[11];
  const float* k_w_paper    = (const float*)d_in[12];
  const float* k_b_paper    = (const float*)d_in[13];
  const float* q_w_paper    = (const float*)d_in[14];
  const float* q_b_paper    = (const float*)d_in[15];
  const float* v_w_paper    = (const float*)d_in[16];
  const float* v_b_paper    = (const float*)d_in[17];
  const float* a_w_paper    = (const float*)d_in[18];
  const float* a_b_paper    = (const float*)d_in[19];
  const float* skip_paper   = (const float*)d_in[20];
  const float* k_w_author   = (const float*)d_in[21];
  const float* k_b_author   = (const float*)d_in[22];
  const float* v_w_author   = (const float*)d_in[25];
  const float* v_b_author   = (const float*)d_in[26];
  const float* a_rel_writes = (const float*)d_in[30];
  const float* m_rel_writes = (const float*)d_in[31];
  const float* p_rel_writes = (const float*)d_in[32];
  const float* a_rel_cites  = (const float*)d_in[33];
  const float* m_rel_cites  = (const float*)d_in[34];
  const float* p_rel_cites  = (const float*)d_in[35];

  float* ws = (float*)d_ws;
  size_t off = 0;
  auto nxt = [&](size_t nfloats) { float* p = ws + off; off += nfloats; return p; };
  ushort_t* hp    = (ushort_t*)nxt((size_t)NP * 64);       // [NP][128] bf16
  ushort_t* ha    = (ushort_t*)nxt((size_t)NA * 64);
  ushort_t* qkv   = (ushort_t*)nxt((size_t)3 * NP * 64);   // q, kr_c, vr_c
  ushort_t* kvw   = (ushort_t*)nxt((size_t)2 * NA * 64);   // kr_w, vr_w
  float*    outp  = nxt((size_t)NP * HID);
  unsigned* mbuf  = (unsigned*)nxt((size_t)NP * 4);
  float*    sbuf  = nxt((size_t)NP * 4);
  float*    alpha = nxt((size_t)EW * 4);
  ushort_t* Wall  = (ushort_t*)nxt(65536);                 // 131072 bf16
  float*    Ball  = nxt(5 * 128);
  float*    Wg    = nxt(2048);
  float*    Wh    = nxt(2048);
  float*    bo    = nxt(16);

  ushort_t* q_p  = qkv;
  ushort_t* kr_c = qkv + (size_t)NP * HID;
  ushort_t* vr_c = qkv + (size_t)2 * NP * HID;
  ushort_t* kr_w = kvw;
  ushort_t* vr_w = kvw + (size_t)NA * HID;

  prep_weights<<<7, 256, 0, stream>>>(q_w_paper, q_b_paper,
                                      k_w_paper, k_b_paper, a_rel_cites,
                                      v_w_paper, v_b_paper, m_rel_cites,
                                      k_w_author, k_b_author, a_rel_writes,
                                      v_w_author, v_b_author, m_rel_writes,
                                      lin_paper_w, lin_author_w, Wall, Ball);
  epi_prep<<<1, 256, 0, stream>>>(a_w_paper, a_b_paper, skip_paper, lin_out_w, lin_out_b,
                                  Wg, Wh, bo);

  // input projections (f32 A, relu, bf16 out)
  gemm_mfma<256, true, true><<<dim3((NP + 127) / 128, 1), 256, 0, stream>>>(
      x_paper, Wall + 6 * 16384, lin_paper_b, hp, NP, 0);
  gemm_mfma<128, true, true><<<dim3((NA + 127) / 128, 1), 256, 0, stream>>>(
      x_author, Wall + 5 * 16384, lin_author_b, ha, NA, 0);
  // fused q / kr_c / vr_c (bf16 A)
  gemm_mfma<128, false, false><<<dim3((NP + 127) / 128, 3), 256, 0, stream>>>(
      hp, Wall, Ball, qkv, NP, (long long)NP * HID);
  // fused kr_w / vr_w
  gemm_mfma<128, false, false><<<dim3((NA + 127) / 128, 2), 256, 0, stream>>>(
      ha, Wall + 3 * 16384, Ball + 3 * 128, kvw, NA, (long long)NA * HID);

  hipMemsetAsync(outp, 0, (size_t)NP * HID * sizeof(float), stream);

  // relation: writes (author -> paper)
  hipMemsetAsync(mbuf, 0, (size_t)NP * 4 * sizeof(unsigned), stream);
  hipMemsetAsync(sbuf, 0, (size_t)NP * 4 * sizeof(float), stream);
  edge_alpha<<<(EW * 4 + 255) / 256, 256, 0, stream>>>(EW, writes_src, writes_dst, kr_w, q_p,
                                                       p_rel_writes, alpha, mbuf);
  edge_expsum<<<(EW * 4 + 255) / 256, 256, 0, stream>>>(EW, writes_dst, alpha, mbuf, sbuf);
  edge_scatter<<<1024, 256, 0, stream>>>(EW, writes_src, writes_dst, vr_w, alpha, sbuf, outp);

  // relation: cites (paper -> paper)
  hipMemsetAsync(mbuf, 0, (size_t)NP * 4 * sizeof(unsigned), stream);
  hipMemsetAsync(sbuf, 0, (size_t)NP * 4 * sizeof(float), stream);
  edge_alpha<<<(EC * 4 + 255) / 256, 256, 0, stream>>>(EC, cites_src, cites_dst, kr_c, q_p,
                                                       p_rel_cites, alpha, mbuf);
  edge_expsum<<<(EC * 4 + 255) / 256, 256, 0, stream>>>(EC, cites_dst, alpha, mbuf, sbuf);
  edge_scatter<<<1024, 256, 0, stream>>>(EC, cites_src, cites_dst, vr_c, alpha, sbuf, outp);

  epilogue_k<<<(NP + 63) / 64, 256, 0, stream>>>(outp, hp, Wg, Wh, bo, (float*)d_out);
}

// Round 3
// 613.801 us; speedup vs baseline: 1.9642x; 1.2681x over previous
//
#include <hip/hip_runtime.h>
#include <cstdint>

#define NP 200000
#define NA 100000
#define EW 300000
#define EC 300000
#define HID 128
#define FIN_P 256
#define FIN_A 128
#define NOUT 16
#define ATT_SCALE 0.17677669529663687f  // 1/sqrt(32)

#define SCAN_N (2 * NP)     // 400000 (writes groups then cites groups)
#define SCAN_BS 256
#define SCAN_ITEMS 4
#define SCAN_TILE 1024
#define SCAN_NB ((SCAN_N + SCAN_TILE - 1) / SCAN_TILE)  // 391

typedef short s8v __attribute__((ext_vector_type(8)));
typedef float f32x4 __attribute__((ext_vector_type(4)));
typedef unsigned short ushort_t;

// ---------- helpers ----------
__device__ __forceinline__ float gelu_f(float x) {
  return 0.5f * x * (1.0f + erff(x * 0.70710678118654752f));
}
__device__ __forceinline__ ushort_t f2bf(float f) {  // RNE
  unsigned u = __float_as_uint(f);
  return (ushort_t)((u + 0x7FFFu + ((u >> 16) & 1u)) >> 16);
}
__device__ __forceinline__ unsigned pack2bf(float a, float b) {
  return (unsigned)f2bf(a) | ((unsigned)f2bf(b) << 16);
}
__device__ __forceinline__ float bflo(unsigned u) { return __uint_as_float(u << 16); }
__device__ __forceinline__ float bfhi(unsigned u) { return __uint_as_float(u & 0xFFFF0000u); }

// ---------- weight prep: all GEMM B-matrices -> bf16, TRANSPOSED [n][k] ----------
__global__ void prep_weights(
    const float* __restrict__ qw,  const float* __restrict__ qb,
    const float* __restrict__ kwp, const float* __restrict__ kbp, const float* __restrict__ arc,
    const float* __restrict__ vwp, const float* __restrict__ vbp, const float* __restrict__ mrc,
    const float* __restrict__ kwa, const float* __restrict__ kba, const float* __restrict__ arw,
    const float* __restrict__ vwa, const float* __restrict__ vba, const float* __restrict__ mrw,
    const float* __restrict__ lpw, const float* __restrict__ law,
    ushort_t* __restrict__ Wall, float* __restrict__ Ball)
{
  const int b = blockIdx.x, tid = threadIdx.x;
  if (b == 0) {                    // q weights (transpose only)
    for (int idx = tid; idx < 16384; idx += 256) {
      int c = idx >> 7, r = idx & 127;
      Wall[idx] = f2bf(qw[r * 128 + c]);
    }
    for (int c = tid; c < 128; c += 256) Ball[c] = qb[c];
  } else if (b <= 4) {             // combined per-relation K/V weights
    const float *W, *bias, *rel;
    switch (b) {
      case 1:  W = kwp; bias = kbp; rel = arc; break;
      case 2:  W = vwp; bias = vbp; rel = mrc; break;
      case 3:  W = kwa; bias = kba; rel = arw; break;
      default: W = vwa; bias = vba; rel = mrw; break;
    }
    for (int idx = tid; idx < 16384; idx += 256) {
      int c = idx >> 7, r = idx & 127, h = c >> 5, e = c & 31;
      float s = 0.f;
      #pragma unroll
      for (int d = 0; d < 32; ++d) s += W[r * 128 + h * 32 + d] * rel[h * 1024 + d * 32 + e];
      Wall[b * 16384 + idx] = f2bf(s);
    }
    for (int c = tid; c < 128; c += 256) {
      int h = c >> 5, e = c & 31;
      float s = 0.f;
      #pragma unroll
      for (int d = 0; d < 32; ++d) s += bias[h * 32 + d] * rel[h * 1024 + d * 32 + e];
      Ball[b * 128 + c] = s;
    }
  } else if (b == 5) {             // author input-proj
    for (int idx = tid; idx < 16384; idx += 256) {
      int c = idx >> 7, r = idx & 127;
      Wall[5 * 16384 + idx] = f2bf(law[r * 128 + c]);
    }
  } else {                         // paper input-proj [128 n][256 k]
    for (int idx = tid; idx < 32768; idx += 256) {
      int c = idx >> 8, r = idx & 255;
      Wall[6 * 16384 + idx] = f2bf(lpw[r * 128 + c]);
    }
  }
}

// ---------- epilogue weight prep ----------
__global__ void epi_prep(const float* __restrict__ aw, const float* __restrict__ ab,
                         const float* __restrict__ skip, const float* __restrict__ W2,
                         const float* __restrict__ b2,
                         float* __restrict__ Wg, float* __restrict__ Wh, float* __restrict__ bo)
{
  float beta = 1.0f / (1.0f + expf(-skip[0]));
  int tid = threadIdx.x;
  for (int idx = tid; idx < 128 * 16; idx += 256) {
    int r = idx >> 4, c = idx & 15;
    float s = 0.f;
    for (int k = 0; k < 128; ++k) s += aw[r * 128 + k] * W2[k * 16 + c];
    Wg[idx] = beta * s;
    Wh[idx] = (1.0f - beta) * W2[idx];
  }
  if (tid < 16) {
    float s = 0.f;
    for (int k = 0; k < 128; ++k) s += ab[k] * W2[k * 16 + tid];
    bo[tid] = beta * s + b2[tid];
  }
}

// ---------- bf16 MFMA GEMM (unchanged from round 2) ----------
template <int KT, bool AF32, bool RELU>
__global__ __launch_bounds__(256) void gemm_mfma(
    const void* __restrict__ Ap, const ushort_t* __restrict__ Wbase,
    const float* __restrict__ bbase, ushort_t* __restrict__ Cbase,
    int M, long long cstride)
{
  __shared__ ushort_t As[4][128][8];
  __shared__ ushort_t Bs[4][128][8];
  const int tid  = threadIdx.x;
  const int lane = tid & 63;
  const int wv   = tid >> 6;
  const int wr   = wv >> 1, wc = wv & 1;
  const int l15  = lane & 15, kgl = lane >> 4;
  const int row0 = blockIdx.x * 128;
  const ushort_t* W = Wbase + (size_t)blockIdx.y * 128 * KT;
  const float* bias = bbase + (size_t)blockIdx.y * 128;
  ushort_t* C       = Cbase + (size_t)blockIdx.y * cstride;

  f32x4 acc[4][4];
  #pragma unroll
  for (int i = 0; i < 4; ++i)
    #pragma unroll
    for (int j = 0; j < 4; ++j) acc[i][j] = (f32x4){0.f, 0.f, 0.f, 0.f};

  for (int kt = 0; kt < KT; kt += 32) {
    #pragma unroll
    for (int half = 0; half < 2; ++half) {
      int slot = half * 256 + tid;
      int kg = slot >> 7, r = slot & 127;
      int grow = row0 + r; if (grow > M - 1) grow = M - 1;
      if (AF32) {
        const float* ga = (const float*)Ap + (size_t)grow * KT + kt + kg * 8;
        float4 a0 = *(const float4*)ga;
        float4 a1 = *(const float4*)(ga + 4);
        uint4 v;
        v.x = pack2bf(a0.x, a0.y); v.y = pack2bf(a0.z, a0.w);
        v.z = pack2bf(a1.x, a1.y); v.w = pack2bf(a1.z, a1.w);
        *(uint4*)&As[kg][r][0] = v;
      } else {
        *(uint4*)&As[kg][r][0] =
            *(const uint4*)((const ushort_t*)Ap + (size_t)grow * KT + kt + kg * 8);
      }
    }
    #pragma unroll
    for (int half = 0; half < 2; ++half) {
      int slot = half * 256 + tid;
      int kg = slot >> 7, c = slot & 127;
      *(uint4*)&Bs[kg][c][0] = *(const uint4*)(W + (size_t)c * KT + kt + kg * 8);
    }
    __syncthreads();

    const s8v* As8 = (const s8v*)&As[0][0][0];
    const s8v* Bs8 = (const s8v*)&Bs[0][0][0];
    s8v af[4], bfv[4];
    #pragma unroll
    for (int i = 0; i < 4; ++i) af[i]  = As8[kgl * 128 + wr * 64 + i * 16 + l15];
    #pragma unroll
    for (int j = 0; j < 4; ++j) bfv[j] = Bs8[kgl * 128 + wc * 64 + j * 16 + l15];
    #pragma unroll
    for (int i = 0; i < 4; ++i)
      #pragma unroll
      for (int j = 0; j < 4; ++j)
        acc[i][j] = __builtin_amdgcn_mfma_f32_16x16x32_bf16(af[i], bfv[j], acc[i][j], 0, 0, 0);
    __syncthreads();
  }

  float bv[4];
  #pragma unroll
  for (int j = 0; j < 4; ++j) bv[j] = bias[wc * 64 + j * 16 + l15];
  #pragma unroll
  for (int i = 0; i < 4; ++i) {
    #pragma unroll
    for (int r = 0; r < 4; ++r) {
      int row = row0 + wr * 64 + i * 16 + kgl * 4 + r;
      if (row < M) {
        #pragma unroll
        for (int j = 0; j < 4; ++j) {
          float v = acc[i][j][r] + bv[j];
          if (RELU) v = fmaxf(v, 0.f);
          C[(size_t)row * 128 + wc * 64 + j * 16 + l15] = f2bf(v);
        }
      }
    }
  }
}

// ---------- CSR build ----------
__global__ void hist_k(const int* __restrict__ wdst, const int* __restrict__ cdst,
                       int* __restrict__ cnt)
{
  int t = blockIdx.x * blockDim.x + threadIdx.x;
  if (t < EW) atomicAdd(&cnt[wdst[t]], 1);
  if (t < EC) atomicAdd(&cnt[NP + cdst[t]], 1);
}

__global__ __launch_bounds__(SCAN_BS) void scan1(const int* __restrict__ cnt,
                                                 int* __restrict__ off,
                                                 int* __restrict__ bsum)
{
  __shared__ int sh[2][SCAN_BS];
  int tid = threadIdx.x;
  int base = blockIdx.x * SCAN_TILE + tid * SCAN_ITEMS;
  int v[SCAN_ITEMS]; int tsum = 0;
  #pragma unroll
  for (int i = 0; i < SCAN_ITEMS; ++i) {
    int idx = base + i;
    v[i] = (idx < SCAN_N) ? cnt[idx] : 0;
    tsum += v[i];
  }
  int p = 0;
  sh[0][tid] = tsum; __syncthreads();
  #pragma unroll
  for (int d = 1; d < SCAN_BS; d <<= 1) {
    int x = sh[p][tid] + ((tid >= d) ? sh[p][tid - d] : 0);
    sh[p ^ 1][tid] = x; __syncthreads(); p ^= 1;
  }
  int run = sh[p][tid] - tsum;  // exclusive base within block
  #pragma unroll
  for (int i = 0; i < SCAN_ITEMS; ++i) {
    int idx = base + i;
    if (idx < SCAN_N) off[idx] = run;
    run += v[i];
  }
  if (tid == SCAN_BS - 1) bsum[blockIdx.x] = sh[p][tid];
}

__global__ __launch_bounds__(512) void scan2(int* __restrict__ bsum)
{
  __shared__ int sh[2][512];
  int tid = threadIdx.x;
  int v = (tid < SCAN_NB) ? bsum[tid] : 0;
  int p = 0;
  sh[0][tid] = v; __syncthreads();
  for (int d = 1; d < 512; d <<= 1) {
    int x = sh[p][tid] + ((tid >= d) ? sh[p][tid - d] : 0);
    sh[p ^ 1][tid] = x; __syncthreads(); p ^= 1;
  }
  if (tid < SCAN_NB) bsum[tid] = sh[p][tid] - v;  // exclusive
}

__global__ __launch_bounds__(SCAN_BS) void scan3(int* __restrict__ off, int* __restrict__ cur,
                                                 const int* __restrict__ bsum)
{
  int add = bsum[blockIdx.x];
  int base = blockIdx.x * SCAN_TILE + threadIdx.x;
  #pragma unroll
  for (int i = 0; i < SCAN_ITEMS; ++i) {
    int idx = base + i * SCAN_BS;
    if (idx < SCAN_N) { int t = off[idx] + add; off[idx] = t; cur[idx] = t; }
  }
  if (blockIdx.x == 0 && threadIdx.x == 0) off[SCAN_N] = EW + EC;
}

__global__ void fill_k(const int* __restrict__ wsrc, const int* __restrict__ wdst,
                       const int* __restrict__ csrc, const int* __restrict__ cdst,
                       int* __restrict__ cur, int* __restrict__ esrc)
{
  int t = blockIdx.x * blockDim.x + threadIdx.x;
  if (t < EW) { int p = atomicAdd(&cur[wdst[t]], 1); esrc[p] = wsrc[t]; }
  if (t < EC) { int p = atomicAdd(&cur[NP + cdst[t]], 1); esrc[p] = csrc[t]; }
}

// ---------- fused per-node attention: online softmax over both relations ----------
// One wave per paper node. Lane l holds channels 2l, 2l+1 (head = l>>4).
__global__ __launch_bounds__(256) void node_attn(
    const int* __restrict__ off, const int* __restrict__ esrc,
    const ushort_t* __restrict__ q,
    const ushort_t* __restrict__ kr_w, const ushort_t* __restrict__ vr_w,
    const ushort_t* __restrict__ kr_c, const ushort_t* __restrict__ vr_c,
    const float* __restrict__ p_rel_w, const float* __restrict__ p_rel_c,
    float* __restrict__ out_p)
{
  int wid = (blockIdx.x * blockDim.x + threadIdx.x) >> 6;
  int lane = threadIdx.x & 63;
  if (wid >= NP) return;

  unsigned qw = *(const unsigned*)(q + (size_t)wid * HID + 2 * lane);
  float q0 = bflo(qw), q1 = bfhi(qw);
  int h = lane >> 4;
  float pr[2] = {p_rel_w[h] * ATT_SCALE, p_rel_c[h] * ATT_SCALE};
  int e0[2] = {off[wid], off[NP + wid]};
  int e1[2] = {off[wid + 1], off[NP + wid + 1]};

  float t0 = 0.f, t1 = 0.f;
  #pragma unroll
  for (int r = 0; r < 2; ++r) {
    const ushort_t* kr = (r == 0) ? kr_w : kr_c;
    const ushort_t* vr = (r == 0) ? vr_w : vr_c;
    float m = -1e30f, s = 0.f, a0 = 0.f, a1 = 0.f;
    for (int e = e0[r]; e < e1[r]; ++e) {
      int src = esrc[e];
      unsigned kw = *(const unsigned*)(kr + (size_t)src * HID + 2 * lane);
      float d = q0 * bflo(kw) + q1 * bfhi(kw);
      d += __shfl_xor(d, 1);
      d += __shfl_xor(d, 2);
      d += __shfl_xor(d, 4);
      d += __shfl_xor(d, 8);   // head-sum within 16-lane group
      float a = d * pr[r];
      float nm = fmaxf(m, a);
      float scale = __expf(m - nm);
      float p = __expf(a - nm);
      unsigned vw = *(const unsigned*)(vr + (size_t)src * HID + 2 * lane);
      s = s * scale + p;
      a0 = a0 * scale + p * bflo(vw);
      a1 = a1 * scale + p * bfhi(vw);
      m = nm;
    }
    float inv = 1.0f / (s + 1e-16f);
    t0 += a0 * inv;
    t1 += a1 * inv;
  }
  *(float2*)(out_p + (size_t)wid * HID + 2 * lane) = make_float2(t0, t1);
}

// ---------- fused epilogue: out = gelu(out_p)@Wg + hp@Wh + bo ----------
__global__ __launch_bounds__(256) void epilogue_k(
    const float* __restrict__ out_p, const ushort_t* __restrict__ hp,
    const float* __restrict__ Wg, const float* __restrict__ Wh,
    const float* __restrict__ bo, float* __restrict__ out)
{
  __shared__ float Ts[64][129];
  __shared__ float Wgs[128][16];
  __shared__ float Whs[128][16];
  __shared__ float bs[16];
  int tid = threadIdx.x;
  int row0 = blockIdx.x * 64;

  #pragma unroll
  for (int i = 0; i < 2; ++i) {
    int idx = tid + i * 256;
    *(float4*)&Wgs[idx >> 2][(idx & 3) << 2] = *(const float4*)(Wg + (size_t)idx * 4);
    *(float4*)&Whs[idx >> 2][(idx & 3) << 2] = *(const float4*)(Wh + (size_t)idx * 4);
  }
  if (tid < 16) bs[tid] = bo[tid];

  #pragma unroll
  for (int i = 0; i < 8; ++i) {
    int idx = tid + i * 256;
    int r = idx >> 5, c4 = (idx & 31) << 2;
    float4 g = *(const float4*)(out_p + (size_t)(row0 + r) * HID + c4);
    Ts[r][c4 + 0] = gelu_f(g.x); Ts[r][c4 + 1] = gelu_f(g.y);
    Ts[r][c4 + 2] = gelu_f(g.z); Ts[r][c4 + 3] = gelu_f(g.w);
  }
  __syncthreads();

  int row = tid & 63, cg = tid >> 6;
  float acc[4];
  #pragma unroll
  for (int j = 0; j < 4; ++j) acc[j] = bs[cg * 4 + j];
  for (int k = 0; k < 128; ++k) {
    float g = Ts[row][k];
    float4 w = *(const float4*)&Wgs[k][cg << 2];
    acc[0] = fmaf(g, w.x, acc[0]); acc[1] = fmaf(g, w.y, acc[1]);
    acc[2] = fmaf(g, w.z, acc[2]); acc[3] = fmaf(g, w.w, acc[3]);
  }
  __syncthreads();

  #pragma unroll
  for (int i = 0; i < 4; ++i) {
    int idx = tid + i * 256;
    int r = idx >> 4, c8 = (idx & 15) << 3;
    uint4 hh = *(const uint4*)(hp + (size_t)(row0 + r) * HID + c8);
    const unsigned* pw = (const unsigned*)&hh;
    #pragma unroll
    for (int w = 0; w < 4; ++w) {
      Ts[r][c8 + 2 * w]     = bflo(pw[w]);
      Ts[r][c8 + 2 * w + 1] = bfhi(pw[w]);
    }
  }
  __syncthreads();
  for (int k = 0; k < 128; ++k) {
    float hv = Ts[row][k];
    float4 w = *(const float4*)&Whs[k][cg << 2];
    acc[0] = fmaf(hv, w.x, acc[0]); acc[1] = fmaf(hv, w.y, acc[1]);
    acc[2] = fmaf(hv, w.z, acc[2]); acc[3] = fmaf(hv, w.w, acc[3]);
  }
  *(float4*)(out + (size_t)(row0 + row) * NOUT + (cg << 2)) =
      make_float4(acc[0], acc[1], acc[2], acc[3]);
}

// ---------- launch ----------
extern "C" void kernel_launch(void* const* d_in, const int* in_sizes, int n_in,
                              void* d_out, int out_size, void* d_ws, size_t ws_size,
                              hipStream_t stream)
{
  (void)in_sizes; (void)n_in; (void)out_size; (void)ws_size;
  const float* x_paper      = (const float*)d_in[0];
  const float* x_author     = (const float*)d_in[1];
  const int*   writes_src   = (const int*)d_in[2];
  const int*   writes_dst   = (const int*)d_in[3];
  const int*   cites_src    = (const int*)d_in[4];
  const int*   cites_dst    = (const int*)d_in[5];
  const float* lin_paper_w  = (const float*)d_in[6];
  const float* lin_paper_b  = (const float*)d_in[7];
  const float* lin_author_w = (const float*)d_in[8];
  const float* lin_author_b = (const float*)d_in[9];
  const float* lin_out_w    = (const float*)d_in[10];
  const float* lin_out_b    = (const float*)d_in[11];
  const float* k_w_paper    = (const float*)d_in[12];
  const float* k_b_paper    = (const float*)d_in[13];
  const float* q_w_paper    = (const float*)d_in[14];
  const float* q_b_paper    = (const float*)d_in[15];
  const float* v_w_paper    = (const float*)d_in[16];
  const float* v_b_paper    = (const float*)d_in[17];
  const float* a_w_paper    = (const float*)d_in[18];
  const float* a_b_paper    = (const float*)d_in[19];
  const float* skip_paper   = (const float*)d_in[20];
  const float* k_w_author   = (const float*)d_in[21];
  const float* k_b_author   = (const float*)d_in[22];
  const float* v_w_author   = (const float*)d_in[25];
  const float* v_b_author   = (const float*)d_in[26];
  const float* a_rel_writes = (const float*)d_in[30];
  const float* m_rel_writes = (const float*)d_in[31];
  const float* p_rel_writes = (const float*)d_in[32];
  const float* a_rel_cites  = (const float*)d_in[33];
  const float* m_rel_cites  = (const float*)d_in[34];
  const float* p_rel_cites  = (const float*)d_in[35];

  float* ws = (float*)d_ws;
  size_t off_f = 0;
  auto nxt = [&](size_t nfloats) { float* p = ws + off_f; off_f += nfloats; return p; };
  ushort_t* hp    = (ushort_t*)nxt((size_t)NP * 64);       // [NP][128] bf16
  ushort_t* ha    = (ushort_t*)nxt((size_t)NA * 64);
  ushort_t* qkv   = (ushort_t*)nxt((size_t)3 * NP * 64);   // q, kr_c, vr_c
  ushort_t* kvw   = (ushort_t*)nxt((size_t)2 * NA * 64);   // kr_w, vr_w
  float*    outp  = nxt((size_t)NP * HID);
  int*      cnt   = (int*)nxt(SCAN_N);
  int*      offs  = (int*)nxt(SCAN_N + 2);
  int*      cur   = (int*)nxt(SCAN_N);
  int*      esrc  = (int*)nxt(EW + EC);
  int*      bsum  = (int*)nxt(512);
  ushort_t* Wall  = (ushort_t*)nxt(65536);
  float*    Ball  = nxt(5 * 128);
  float*    Wg    = nxt(2048);
  float*    Wh    = nxt(2048);
  float*    bo    = nxt(16);

  ushort_t* q_p  = qkv;
  ushort_t* kr_c = qkv + (size_t)NP * HID;
  ushort_t* vr_c = qkv + (size_t)2 * NP * HID;
  ushort_t* kr_w = kvw;
  ushort_t* vr_w = kvw + (size_t)NA * HID;

  // --- weight prep ---
  prep_weights<<<7, 256, 0, stream>>>(q_w_paper, q_b_paper,
                                      k_w_paper, k_b_paper, a_rel_cites,
                                      v_w_paper, v_b_paper, m_rel_cites,
                                      k_w_author, k_b_author, a_rel_writes,
                                      v_w_author, v_b_author, m_rel_writes,
                                      lin_paper_w, lin_author_w, Wall, Ball);
  epi_prep<<<1, 256, 0, stream>>>(a_w_paper, a_b_paper, skip_paper, lin_out_w, lin_out_b,
                                  Wg, Wh, bo);

  // --- CSR build (independent of GEMMs) ---
  hipMemsetAsync(cnt, 0, (size_t)SCAN_N * sizeof(int), stream);
  hist_k<<<(300000 + 255) / 256, 256, 0, stream>>>(writes_dst, cites_dst, cnt);
  scan1<<<SCAN_NB, SCAN_BS, 0, stream>>>(cnt, offs, bsum);
  scan2<<<1, 512, 0, stream>>>(bsum);
  scan3<<<SCAN_NB, SCAN_BS, 0, stream>>>(offs, cur, bsum);
  fill_k<<<(300000 + 255) / 256, 256, 0, stream>>>(writes_src, writes_dst,
                                                   cites_src, cites_dst, cur, esrc);

  // --- GEMMs ---
  gemm_mfma<256, true, true><<<dim3((NP + 127) / 128, 1), 256, 0, stream>>>(
      x_paper, Wall + 6 * 16384, lin_paper_b, hp, NP, 0);
  gemm_mfma<128, true, true><<<dim3((NA + 127) / 128, 1), 256, 0, stream>>>(
      x_author, Wall + 5 * 16384, lin_author_b, ha, NA, 0);
  gemm_mfma<128, false, false><<<dim3((NP + 127) / 128, 3), 256, 0, stream>>>(
      hp, Wall, Ball, qkv, NP, (long long)NP * HID);
  gemm_mfma<128, false, false><<<dim3((NA + 127) / 128, 2), 256, 0, stream>>>(
      ha, Wall + 3 * 16384, Ball + 3 * 128, kvw, NA, (long long)NA * HID);

  // --- fused edge-softmax attention, one wave per node ---
  node_attn<<<(NP * 64 + 255) / 256, 256, 0, stream>>>(
      offs, esrc, q_p, kr_w, vr_w, kr_c, vr_c, p_rel_writes, p_rel_cites, outp);

  // --- epilogue ---
  epilogue_k<<<(NP + 63) / 64, 256, 0, stream>>>(outp, hp, Wg, Wh, bo, (float*)d_out);
}

// Round 4
// 580.356 us; speedup vs baseline: 2.0773x; 1.0576x over previous
//
#include <hip/hip_runtime.h>
#include <cstdint>

#define NP 200000
#define NA 100000
#define EW 300000
#define EC 300000
#define HID 128
#define FIN_P 256
#define FIN_A 128
#define NOUT 16
#define ATT_SCALE 0.17677669529663687f  // 1/sqrt(32)

#define SCAN_N (2 * NP)     // 400000 (writes groups then cites groups)
#define SCAN_BS 256
#define SCAN_ITEMS 4
#define SCAN_TILE 1024
#define SCAN_NB ((SCAN_N + SCAN_TILE - 1) / SCAN_TILE)  // 391

typedef short s8v __attribute__((ext_vector_type(8)));
typedef float f32x4 __attribute__((ext_vector_type(4)));
typedef unsigned short ushort_t;

// ---------- helpers ----------
__device__ __forceinline__ float gelu_f(float x) {
  return 0.5f * x * (1.0f + erff(x * 0.70710678118654752f));
}
__device__ __forceinline__ ushort_t f2bf(float f) {  // RNE
  unsigned u = __float_as_uint(f);
  return (ushort_t)((u + 0x7FFFu + ((u >> 16) & 1u)) >> 16);
}
__device__ __forceinline__ unsigned pack2bf(float a, float b) {
  return (unsigned)f2bf(a) | ((unsigned)f2bf(b) << 16);
}
__device__ __forceinline__ float bflo(unsigned u) { return __uint_as_float(u << 16); }
__device__ __forceinline__ float bfhi(unsigned u) { return __uint_as_float(u & 0xFFFF0000u); }

// ---------- weight prep: all GEMM B-matrices -> bf16, TRANSPOSED [n][k] ----------
__global__ void prep_weights(
    const float* __restrict__ qw,  const float* __restrict__ qb,
    const float* __restrict__ kwp, const float* __restrict__ kbp, const float* __restrict__ arc,
    const float* __restrict__ vwp, const float* __restrict__ vbp, const float* __restrict__ mrc,
    const float* __restrict__ kwa, const float* __restrict__ kba, const float* __restrict__ arw,
    const float* __restrict__ vwa, const float* __restrict__ vba, const float* __restrict__ mrw,
    const float* __restrict__ lpw, const float* __restrict__ law,
    ushort_t* __restrict__ Wall, float* __restrict__ Ball)
{
  const int b = blockIdx.x, tid = threadIdx.x;
  if (b == 0) {                    // q weights (transpose only)
    for (int idx = tid; idx < 16384; idx += 256) {
      int c = idx >> 7, r = idx & 127;
      Wall[idx] = f2bf(qw[r * 128 + c]);
    }
    for (int c = tid; c < 128; c += 256) Ball[c] = qb[c];
  } else if (b <= 4) {             // combined per-relation K/V weights
    const float *W, *bias, *rel;
    switch (b) {
      case 1:  W = kwp; bias = kbp; rel = arc; break;
      case 2:  W = vwp; bias = vbp; rel = mrc; break;
      case 3:  W = kwa; bias = kba; rel = arw; break;
      default: W = vwa; bias = vba; rel = mrw; break;
    }
    for (int idx = tid; idx < 16384; idx += 256) {
      int c = idx >> 7, r = idx & 127, h = c >> 5, e = c & 31;
      float s = 0.f;
      #pragma unroll
      for (int d = 0; d < 32; ++d) s += W[r * 128 + h * 32 + d] * rel[h * 1024 + d * 32 + e];
      Wall[b * 16384 + idx] = f2bf(s);
    }
    for (int c = tid; c < 128; c += 256) {
      int h = c >> 5, e = c & 31;
      float s = 0.f;
      #pragma unroll
      for (int d = 0; d < 32; ++d) s += bias[h * 32 + d] * rel[h * 1024 + d * 32 + e];
      Ball[b * 128 + c] = s;
    }
  } else if (b == 5) {             // author input-proj
    for (int idx = tid; idx < 16384; idx += 256) {
      int c = idx >> 7, r = idx & 127;
      Wall[5 * 16384 + idx] = f2bf(law[r * 128 + c]);
    }
  } else {                         // paper input-proj [128 n][256 k]
    for (int idx = tid; idx < 32768; idx += 256) {
      int c = idx >> 8, r = idx & 255;
      Wall[6 * 16384 + idx] = f2bf(lpw[r * 128 + c]);
    }
  }
}

// ---------- epilogue weight prep ----------
__global__ void epi_prep(const float* __restrict__ aw, const float* __restrict__ ab,
                         const float* __restrict__ skip, const float* __restrict__ W2,
                         const float* __restrict__ b2,
                         float* __restrict__ Wg, float* __restrict__ Wh, float* __restrict__ bo)
{
  float beta = 1.0f / (1.0f + expf(-skip[0]));
  int tid = threadIdx.x;
  for (int idx = tid; idx < 128 * 16; idx += 256) {
    int r = idx >> 4, c = idx & 15;
    float s = 0.f;
    for (int k = 0; k < 128; ++k) s += aw[r * 128 + k] * W2[k * 16 + c];
    Wg[idx] = beta * s;
    Wh[idx] = (1.0f - beta) * W2[idx];
  }
  if (tid < 16) {
    float s = 0.f;
    for (int k = 0; k < 128; ++k) s += ab[k] * W2[k * 16 + tid];
    bo[tid] = beta * s + b2[tid];
  }
}

// ---------- bf16 MFMA GEMM ----------
template <int KT, bool AF32, bool RELU>
__global__ __launch_bounds__(256) void gemm_mfma(
    const void* __restrict__ Ap, const ushort_t* __restrict__ Wbase,
    const float* __restrict__ bbase, ushort_t* __restrict__ Cbase,
    int M, long long cstride)
{
  __shared__ ushort_t As[4][128][8];
  __shared__ ushort_t Bs[4][128][8];
  const int tid  = threadIdx.x;
  const int lane = tid & 63;
  const int wv   = tid >> 6;
  const int wr   = wv >> 1, wc = wv & 1;
  const int l15  = lane & 15, kgl = lane >> 4;
  const int row0 = blockIdx.x * 128;
  const ushort_t* W = Wbase + (size_t)blockIdx.y * 128 * KT;
  const float* bias = bbase + (size_t)blockIdx.y * 128;
  ushort_t* C       = Cbase + (size_t)blockIdx.y * cstride;

  f32x4 acc[4][4];
  #pragma unroll
  for (int i = 0; i < 4; ++i)
    #pragma unroll
    for (int j = 0; j < 4; ++j) acc[i][j] = (f32x4){0.f, 0.f, 0.f, 0.f};

  for (int kt = 0; kt < KT; kt += 32) {
    #pragma unroll
    for (int half = 0; half < 2; ++half) {
      int slot = half * 256 + tid;
      int kg = slot >> 7, r = slot & 127;
      int grow = row0 + r; if (grow > M - 1) grow = M - 1;
      if (AF32) {
        const float* ga = (const float*)Ap + (size_t)grow * KT + kt + kg * 8;
        float4 a0 = *(const float4*)ga;
        float4 a1 = *(const float4*)(ga + 4);
        uint4 v;
        v.x = pack2bf(a0.x, a0.y); v.y = pack2bf(a0.z, a0.w);
        v.z = pack2bf(a1.x, a1.y); v.w = pack2bf(a1.z, a1.w);
        *(uint4*)&As[kg][r][0] = v;
      } else {
        *(uint4*)&As[kg][r][0] =
            *(const uint4*)((const ushort_t*)Ap + (size_t)grow * KT + kt + kg * 8);
      }
    }
    #pragma unroll
    for (int half = 0; half < 2; ++half) {
      int slot = half * 256 + tid;
      int kg = slot >> 7, c = slot & 127;
      *(uint4*)&Bs[kg][c][0] = *(const uint4*)(W + (size_t)c * KT + kt + kg * 8);
    }
    __syncthreads();

    const s8v* As8 = (const s8v*)&As[0][0][0];
    const s8v* Bs8 = (const s8v*)&Bs[0][0][0];
    s8v af[4], bfv[4];
    #pragma unroll
    for (int i = 0; i < 4; ++i) af[i]  = As8[kgl * 128 + wr * 64 + i * 16 + l15];
    #pragma unroll
    for (int j = 0; j < 4; ++j) bfv[j] = Bs8[kgl * 128 + wc * 64 + j * 16 + l15];
    #pragma unroll
    for (int i = 0; i < 4; ++i)
      #pragma unroll
      for (int j = 0; j < 4; ++j)
        acc[i][j] = __builtin_amdgcn_mfma_f32_16x16x32_bf16(af[i], bfv[j], acc[i][j], 0, 0, 0);
    __syncthreads();
  }

  float bv[4];
  #pragma unroll
  for (int j = 0; j < 4; ++j) bv[j] = bias[wc * 64 + j * 16 + l15];
  #pragma unroll
  for (int i = 0; i < 4; ++i) {
    #pragma unroll
    for (int r = 0; r < 4; ++r) {
      int row = row0 + wr * 64 + i * 16 + kgl * 4 + r;
      if (row < M) {
        #pragma unroll
        for (int j = 0; j < 4; ++j) {
          float v = acc[i][j][r] + bv[j];
          if (RELU) v = fmaxf(v, 0.f);
          C[(size_t)row * 128 + wc * 64 + j * 16 + l15] = f2bf(v);
        }
      }
    }
  }
}

// ---------- CSR build ----------
__global__ void hist_k(const int* __restrict__ wdst, const int* __restrict__ cdst,
                       int* __restrict__ cnt)
{
  int t = blockIdx.x * blockDim.x + threadIdx.x;
  if (t < EW) atomicAdd(&cnt[wdst[t]], 1);
  if (t < EC) atomicAdd(&cnt[NP + cdst[t]], 1);
}

__global__ __launch_bounds__(SCAN_BS) void scan1(const int* __restrict__ cnt,
                                                 int* __restrict__ off,
                                                 int* __restrict__ bsum)
{
  __shared__ int sh[2][SCAN_BS];
  int tid = threadIdx.x;
  int base = blockIdx.x * SCAN_TILE + tid * SCAN_ITEMS;
  int v[SCAN_ITEMS]; int tsum = 0;
  #pragma unroll
  for (int i = 0; i < SCAN_ITEMS; ++i) {
    int idx = base + i;
    v[i] = (idx < SCAN_N) ? cnt[idx] : 0;
    tsum += v[i];
  }
  int p = 0;
  sh[0][tid] = tsum; __syncthreads();
  #pragma unroll
  for (int d = 1; d < SCAN_BS; d <<= 1) {
    int x = sh[p][tid] + ((tid >= d) ? sh[p][tid - d] : 0);
    sh[p ^ 1][tid] = x; __syncthreads(); p ^= 1;
  }
  int run = sh[p][tid] - tsum;  // exclusive base within block
  #pragma unroll
  for (int i = 0; i < SCAN_ITEMS; ++i) {
    int idx = base + i;
    if (idx < SCAN_N) off[idx] = run;
    run += v[i];
  }
  if (tid == SCAN_BS - 1) bsum[blockIdx.x] = sh[p][tid];
}

__global__ __launch_bounds__(512) void scan2(int* __restrict__ bsum)
{
  __shared__ int sh[2][512];
  int tid = threadIdx.x;
  int v = (tid < SCAN_NB) ? bsum[tid] : 0;
  int p = 0;
  sh[0][tid] = v; __syncthreads();
  for (int d = 1; d < 512; d <<= 1) {
    int x = sh[p][tid] + ((tid >= d) ? sh[p][tid - d] : 0);
    sh[p ^ 1][tid] = x; __syncthreads(); p ^= 1;
  }
  if (tid < SCAN_NB) bsum[tid] = sh[p][tid] - v;  // exclusive
}

__global__ __launch_bounds__(SCAN_BS) void scan3(int* __restrict__ off, int* __restrict__ cur,
                                                 const int* __restrict__ bsum)
{
  int add = bsum[blockIdx.x];
  int base = blockIdx.x * SCAN_TILE + threadIdx.x;
  #pragma unroll
  for (int i = 0; i < SCAN_ITEMS; ++i) {
    int idx = base + i * SCAN_BS;
    if (idx < SCAN_N) { int t = off[idx] + add; off[idx] = t; cur[idx] = t; }
  }
  if (blockIdx.x == 0 && threadIdx.x == 0) off[SCAN_N] = EW + EC;
}

__global__ void fill_k(const int* __restrict__ wsrc, const int* __restrict__ wdst,
                       const int* __restrict__ csrc, const int* __restrict__ cdst,
                       int* __restrict__ cur, int* __restrict__ esrc)
{
  int t = blockIdx.x * blockDim.x + threadIdx.x;
  if (t < EW) { int p = atomicAdd(&cur[wdst[t]], 1); esrc[p] = wsrc[t]; }
  if (t < EC) { int p = atomicAdd(&cur[NP + cdst[t]], 1); esrc[p] = csrc[t]; }
}

// ---------- fused per-node attention: batched online softmax, both relations ----------
// One wave per paper node. Lane l holds channels 2l, 2l+1 (head = l>>4).
// B=4 edge batches: 8 concurrent gathers (4 K + 4 V) per batch, one rescale per batch.
__global__ __launch_bounds__(256) void node_attn(
    const int* __restrict__ off, const int* __restrict__ esrc,
    const ushort_t* __restrict__ q,
    const ushort_t* __restrict__ kr_w, const ushort_t* __restrict__ vr_w,
    const ushort_t* __restrict__ kr_c, const ushort_t* __restrict__ vr_c,
    const float* __restrict__ p_rel_w, const float* __restrict__ p_rel_c,
    ushort_t* __restrict__ out_p)
{
  int wid = (blockIdx.x * blockDim.x + threadIdx.x) >> 6;
  int lane = threadIdx.x & 63;
  if (wid >= NP) return;

  unsigned qw = *(const unsigned*)(q + (size_t)wid * HID + 2 * lane);
  float q0 = bflo(qw), q1 = bfhi(qw);
  int h = lane >> 4;
  float prw = p_rel_w[h] * ATT_SCALE;
  float prc = p_rel_c[h] * ATT_SCALE;
  int eb0 = __builtin_amdgcn_readfirstlane(off[wid]);
  int ee0 = __builtin_amdgcn_readfirstlane(off[wid + 1]);
  int eb1 = __builtin_amdgcn_readfirstlane(off[NP + wid]);
  int ee1 = __builtin_amdgcn_readfirstlane(off[NP + wid + 1]);

  float t0 = 0.f, t1 = 0.f;
  #pragma unroll
  for (int r = 0; r < 2; ++r) {
    const ushort_t* kr = (r == 0) ? kr_w : kr_c;
    const ushort_t* vr = (r == 0) ? vr_w : vr_c;
    float prr = (r == 0) ? prw : prc;
    int e  = (r == 0) ? eb0 : eb1;
    int ee = (r == 0) ? ee0 : ee1;
    float m = -1e30f, s = 0.f, a0 = 0.f, a1 = 0.f;
    while (e < ee) {
      int n = ee - e; if (n > 4) n = 4;
      // indices (wave-uniform addresses); clamp tail to edge 0 of batch -> loads stay unconditional
      int srcs[4];
      #pragma unroll
      for (int i = 0; i < 4; ++i) srcs[i] = esrc[e + ((i < n) ? i : 0)];
      // issue all 8 gathers concurrently (V is independent of alpha)
      unsigned kwv[4], vwv[4];
      #pragma unroll
      for (int i = 0; i < 4; ++i) {
        kwv[i] = *(const unsigned*)(kr + (size_t)srcs[i] * HID + 2 * lane);
        vwv[i] = *(const unsigned*)(vr + (size_t)srcs[i] * HID + 2 * lane);
      }
      // 4 independent dot+shfl trees
      float a[4];
      #pragma unroll
      for (int i = 0; i < 4; ++i) {
        float d = q0 * bflo(kwv[i]) + q1 * bfhi(kwv[i]);
        d += __shfl_xor(d, 1);
        d += __shfl_xor(d, 2);
        d += __shfl_xor(d, 4);
        d += __shfl_xor(d, 8);
        a[i] = (i < n) ? d * prr : -1e30f;
      }
      // batched online-softmax update (one rescale per batch)
      float nm = m;
      #pragma unroll
      for (int i = 0; i < 4; ++i) nm = fmaxf(nm, a[i]);
      float sc = __expf(m - nm);
      s *= sc; a0 *= sc; a1 *= sc;
      #pragma unroll
      for (int i = 0; i < 4; ++i) {
        if (i < n) {
          float p = __expf(a[i] - nm);
          s += p;
          a0 += p * bflo(vwv[i]);
          a1 += p * bfhi(vwv[i]);
        }
      }
      m = nm;
      e += n;
    }
    float inv = 1.0f / (s + 1e-16f);
    t0 += a0 * inv;
    t1 += a1 * inv;
  }
  ((unsigned*)out_p)[(size_t)wid * 64 + lane] = pack2bf(t0, t1);
}

// ---------- fused epilogue: out = gelu(out_p)@Wg + hp@Wh + bo  (bf16 out_p, bf16 hp) ----------
__global__ __launch_bounds__(256) void epilogue_k(
    const ushort_t* __restrict__ out_p, const ushort_t* __restrict__ hp,
    const float* __restrict__ Wg, const float* __restrict__ Wh,
    const float* __restrict__ bo, float* __restrict__ out)
{
  __shared__ float Ts[64][129];
  __shared__ float Wgs[128][16];
  __shared__ float Whs[128][16];
  __shared__ float bs[16];
  int tid = threadIdx.x;
  int row0 = blockIdx.x * 64;

  #pragma unroll
  for (int i = 0; i < 2; ++i) {
    int idx = tid + i * 256;
    *(float4*)&Wgs[idx >> 2][(idx & 3) << 2] = *(const float4*)(Wg + (size_t)idx * 4);
    *(float4*)&Whs[idx >> 2][(idx & 3) << 2] = *(const float4*)(Wh + (size_t)idx * 4);
  }
  if (tid < 16) bs[tid] = bo[tid];

  // pass 1: gelu(out_p) tile (bf16 -> f32)
  #pragma unroll
  for (int i = 0; i < 4; ++i) {
    int idx = tid + i * 256;
    int r = idx >> 4, c8 = (idx & 15) << 3;
    uint4 g = *(const uint4*)(out_p + (size_t)(row0 + r) * HID + c8);
    const unsigned* pw = (const unsigned*)&g;
    #pragma unroll
    for (int w = 0; w < 4; ++w) {
      Ts[r][c8 + 2 * w]     = gelu_f(bflo(pw[w]));
      Ts[r][c8 + 2 * w + 1] = gelu_f(bfhi(pw[w]));
    }
  }
  __syncthreads();

  int row = tid & 63, cg = tid >> 6;
  float acc[4];
  #pragma unroll
  for (int j = 0; j < 4; ++j) acc[j] = bs[cg * 4 + j];
  for (int k = 0; k < 128; ++k) {
    float g = Ts[row][k];
    float4 w = *(const float4*)&Wgs[k][cg << 2];
    acc[0] = fmaf(g, w.x, acc[0]); acc[1] = fmaf(g, w.y, acc[1]);
    acc[2] = fmaf(g, w.z, acc[2]); acc[3] = fmaf(g, w.w, acc[3]);
  }
  __syncthreads();

  // pass 2: hp tile (bf16 -> f32)
  #pragma unroll
  for (int i = 0; i < 4; ++i) {
    int idx = tid + i * 256;
    int r = idx >> 4, c8 = (idx & 15) << 3;
    uint4 hh = *(const uint4*)(hp + (size_t)(row0 + r) * HID + c8);
    const unsigned* pw = (const unsigned*)&hh;
    #pragma unroll
    for (int w = 0; w < 4; ++w) {
      Ts[r][c8 + 2 * w]     = bflo(pw[w]);
      Ts[r][c8 + 2 * w + 1] = bfhi(pw[w]);
    }
  }
  __syncthreads();
  for (int k = 0; k < 128; ++k) {
    float hv = Ts[row][k];
    float4 w = *(const float4*)&Whs[k][cg << 2];
    acc[0] = fmaf(hv, w.x, acc[0]); acc[1] = fmaf(hv, w.y, acc[1]);
    acc[2] = fmaf(hv, w.z, acc[2]); acc[3] = fmaf(hv, w.w, acc[3]);
  }
  *(float4*)(out + (size_t)(row0 + row) * NOUT + (cg << 2)) =
      make_float4(acc[0], acc[1], acc[2], acc[3]);
}

// ---------- launch ----------
extern "C" void kernel_launch(void* const* d_in, const int* in_sizes, int n_in,
                              void* d_out, int out_size, void* d_ws, size_t ws_size,
                              hipStream_t stream)
{
  (void)in_sizes; (void)n_in; (void)out_size; (void)ws_size;
  const float* x_paper      = (const float*)d_in[0];
  const float* x_author     = (const float*)d_in[1];
  const int*   writes_src   = (const int*)d_in[2];
  const int*   writes_dst   = (const int*)d_in[3];
  const int*   cites_src    = (const int*)d_in[4];
  const int*   cites_dst    = (const int*)d_in[5];
  const float* lin_paper_w  = (const float*)d_in[6];
  const float* lin_paper_b  = (const float*)d_in[7];
  const float* lin_author_w = (const float*)d_in[8];
  const float* lin_author_b = (const float*)d_in[9];
  const float* lin_out_w    = (const float*)d_in[10];
  const float* lin_out_b    = (const float*)d_in[11];
  const float* k_w_paper    = (const float*)d_in[12];
  const float* k_b_paper    = (const float*)d_in[13];
  const float* q_w_paper    = (const float*)d_in[14];
  const float* q_b_paper    = (const float*)d_in[15];
  const float* v_w_paper    = (const float*)d_in[16];
  const float* v_b_paper    = (const float*)d_in[17];
  const float* a_w_paper    = (const float*)d_in[18];
  const float* a_b_paper    = (const float*)d_in[19];
  const float* skip_paper   = (const float*)d_in[20];
  const float* k_w_author   = (const float*)d_in[21];
  const float* k_b_author   = (const float*)d_in[22];
  const float* v_w_author   = (const float*)d_in[25];
  const float* v_b_author   = (const float*)d_in[26];
  const float* a_rel_writes = (const float*)d_in[30];
  const float* m_rel_writes = (const float*)d_in[31];
  const float* p_rel_writes = (const float*)d_in[32];
  const float* a_rel_cites  = (const float*)d_in[33];
  const float* m_rel_cites  = (const float*)d_in[34];
  const float* p_rel_cites  = (const float*)d_in[35];

  float* ws = (float*)d_ws;
  size_t off_f = 0;
  auto nxt = [&](size_t nfloats) { float* p = ws + off_f; off_f += nfloats; return p; };
  ushort_t* hp    = (ushort_t*)nxt((size_t)NP * 64);       // [NP][128] bf16
  ushort_t* ha    = (ushort_t*)nxt((size_t)NA * 64);
  ushort_t* qkv   = (ushort_t*)nxt((size_t)3 * NP * 64);   // q, kr_c, vr_c
  ushort_t* kvw   = (ushort_t*)nxt((size_t)2 * NA * 64);   // kr_w, vr_w
  ushort_t* outp  = (ushort_t*)nxt((size_t)NP * 64);       // [NP][128] bf16
  int*      cnt   = (int*)nxt(SCAN_N);
  int*      offs  = (int*)nxt(SCAN_N + 2);
  int*      cur   = (int*)nxt(SCAN_N);
  int*      esrc  = (int*)nxt(EW + EC);
  int*      bsum  = (int*)nxt(512);
  ushort_t* Wall  = (ushort_t*)nxt(65536);
  float*    Ball  = nxt(5 * 128);
  float*    Wg    = nxt(2048);
  float*    Wh    = nxt(2048);
  float*    bo    = nxt(16);

  ushort_t* q_p  = qkv;
  ushort_t* kr_c = qkv + (size_t)NP * HID;
  ushort_t* vr_c = qkv + (size_t)2 * NP * HID;
  ushort_t* kr_w = kvw;
  ushort_t* vr_w = kvw + (size_t)NA * HID;

  // --- weight prep ---
  prep_weights<<<7, 256, 0, stream>>>(q_w_paper, q_b_paper,
                                      k_w_paper, k_b_paper, a_rel_cites,
                                      v_w_paper, v_b_paper, m_rel_cites,
                                      k_w_author, k_b_author, a_rel_writes,
                                      v_w_author, v_b_author, m_rel_writes,
                                      lin_paper_w, lin_author_w, Wall, Ball);
  epi_prep<<<1, 256, 0, stream>>>(a_w_paper, a_b_paper, skip_paper, lin_out_w, lin_out_b,
                                  Wg, Wh, bo);

  // --- CSR build (independent of GEMMs) ---
  hipMemsetAsync(cnt, 0, (size_t)SCAN_N * sizeof(int), stream);
  hist_k<<<(300000 + 255) / 256, 256, 0, stream>>>(writes_dst, cites_dst, cnt);
  scan1<<<SCAN_NB, SCAN_BS, 0, stream>>>(cnt, offs, bsum);
  scan2<<<1, 512, 0, stream>>>(bsum);
  scan3<<<SCAN_NB, SCAN_BS, 0, stream>>>(offs, cur, bsum);
  fill_k<<<(300000 + 255) / 256, 256, 0, stream>>>(writes_src, writes_dst,
                                                   cites_src, cites_dst, cur, esrc);

  // --- GEMMs ---
  gemm_mfma<256, true, true><<<dim3((NP + 127) / 128, 1), 256, 0, stream>>>(
      x_paper, Wall + 6 * 16384, lin_paper_b, hp, NP, 0);
  gemm_mfma<128, true, true><<<dim3((NA + 127) / 128, 1), 256, 0, stream>>>(
      x_author, Wall + 5 * 16384, lin_author_b, ha, NA, 0);
  gemm_mfma<128, false, false><<<dim3((NP + 127) / 128, 3), 256, 0, stream>>>(
      hp, Wall, Ball, qkv, NP, (long long)NP * HID);
  gemm_mfma<128, false, false><<<dim3((NA + 127) / 128, 2), 256, 0, stream>>>(
      ha, Wall + 3 * 16384, Ball + 3 * 128, kvw, NA, (long long)NA * HID);

  // --- fused edge-softmax attention, one wave per node ---
  node_attn<<<(NP * 64 + 255) / 256, 256, 0, stream>>>(
      offs, esrc, q_p, kr_w, vr_w, kr_c, vr_c, p_rel_writes, p_rel_cites, outp);

  // --- epilogue ---
  epilogue_k<<<(NP + 63) / 64, 256, 0, stream>>>(outp, hp, Wg, Wh, bo, (float*)d_out);
}